// Round 1
// baseline (380735.400 us; speedup 1.0000x reference)
//
#include <hip/hip_runtime.h>
#include <math.h>

// ---------------------------------------------------------------------------
// 2-layer LSTM, batch=1, T=32768, I=128, H=512  (PyTorch gate order i,f,g,o)
//
// Architecture: ONE persistent kernel, 40 workgroups x 512 threads.
//   WG 0..31  : layer-1. WG w owns h1 indices [w*16, w*16+16) -> 64 gate rows.
//               gates = W_hh1[rows] @ h1[t-1]  +  W_ih1[rows] @ x[t]  + b1
//   WG 32..39 : layer-2 (runs 1 step behind layer 1, same barrier domain).
//               gates = W_ih2[rows] @ h1[tau]  +  W_hh2[rows] @ h2[tau-1] + b2
// Both roles identical shape: 64 rows x (512 primary + 128 secondary) cols.
// Per-lane: 4 rows x (16 + 4) cols = 80 f32 weights held in VGPRs for the
// whole kernel. Per-step communication: h1 (512 f32) / h2 (128 f32) via
// depth-4 rings in d_ws; per-WG monotonic tags + threadfence for sync.
// Lockstep (everyone waits for all 40 tags >= t) bounds skew to 1 step, so
// depth-4 rings cannot be overwritten while still being read.
// ---------------------------------------------------------------------------

#define T_STEPS 32768
#define NL1     32
#define NWG     40
#define BLK     512

// ws layout (u32 indices): [0..63] tags (40 used, [63] = abort flag)
// [1024..3071] h1_ring[4][512] f32 ; [3072..3583] h2_ring[4][128] f32
#define WS_WORDS 4096

__device__ __forceinline__ float sigm(float x) { return 1.0f / (1.0f + __expf(-x)); }
// tanh via exp, safe at +/-inf: e=inf -> 1, e=0 -> -1
__device__ __forceinline__ float tanh_fast(float x) { return 1.0f - 2.0f / (__expf(2.0f * x) + 1.0f); }

__global__ void lstm_init(unsigned int* ws)
{
    int i = blockIdx.x * blockDim.x + threadIdx.x;
    if (i < WS_WORDS) ws[i] = 0u;
}

__global__ __launch_bounds__(BLK, 2) void lstm_persist(
    const float* __restrict__ x,      // [32768][128]
    const float* __restrict__ Wih1,   // [2048][128]
    const float* __restrict__ Whh1,   // [2048][512]
    const float* __restrict__ bih1,
    const float* __restrict__ bhh1,
    const float* __restrict__ Wih2,   // [512][512]
    const float* __restrict__ Whh2,   // [512][128]
    const float* __restrict__ bih2,
    const float* __restrict__ bhh2,
    float* __restrict__ out,          // [32768][128]
    unsigned int* ws)
{
    const int w     = blockIdx.x;
    const bool isL1 = (w < NL1);
    const int tid   = threadIdx.x;
    const int rt    = tid >> 5;   // 0..15 : row-tile (4 rows each)
    const int ct    = tid & 31;   // 0..31 : col-tile (16 primary + 4 secondary cols)

    unsigned int* tag = ws;                    // [40], [63]=abort
    float* h1ring = (float*)(ws + 1024);       // [4][512]
    float* h2ring = (float*)(ws + 3072);       // [4][128]

    __shared__ float part[64][33];             // [row][ct] partials (+1 pad)
    __shared__ float gs[64];                   // gathered row sums

    // ---- role parameters -------------------------------------------------
    const int hb = (isL1 ? w : (w - NL1)) * 16;          // h-index base
    const int Hd = isL1 ? 512 : 128;                     // gate stride (layer hidden)
    const float* WA = isL1 ? Whh1 : Wih2;                // [4*Hd][512]
    const float* WB = isL1 ? Wih1 : Whh2;                // [4*Hd][128]

    // ---- load weights into registers (once) ------------------------------
    float wA[4][16];
    float wB[4][4];
#pragma unroll
    for (int q = 0; q < 4; ++q) {
        const int rl   = rt * 4 + q;          // local row 0..63
        const int g    = rl >> 4;             // gate 0..3 (i,f,g,o)
        const int hl   = rl & 15;
        const int grow = g * Hd + hb + hl;    // global weight row
        const float4* pa = (const float4*)(WA + (size_t)grow * 512 + ct * 16);
#pragma unroll
        for (int jj = 0; jj < 4; ++jj) {
            float4 t4 = pa[jj];
            wA[q][jj * 4 + 0] = t4.x; wA[q][jj * 4 + 1] = t4.y;
            wA[q][jj * 4 + 2] = t4.z; wA[q][jj * 4 + 3] = t4.w;
        }
        float4 tb = *(const float4*)(WB + (size_t)grow * 128 + ct * 4);
        wB[q][0] = tb.x; wB[q][1] = tb.y; wB[q][2] = tb.z; wB[q][3] = tb.w;
    }

    // ---- activation-thread state (threads 0..15) -------------------------
    float bias[4] = {0.f, 0.f, 0.f, 0.f};
    float cst = 0.0f;
    if (tid < 16) {
        const float* bi = isL1 ? bih1 : bih2;
        const float* bh = isL1 ? bhh1 : bhh2;
#pragma unroll
        for (int g = 0; g < 4; ++g)
            bias[g] = bi[g * Hd + hb + tid] + bh[g * Hd + hb + tid];
    }

    // ---- x prefetch (layer-1 secondary operand) --------------------------
    float4 vx = make_float4(0.f, 0.f, 0.f, 0.f);
    if (isL1) vx = *(const float4*)(x + ct * 4);   // x[0]

    // ---- time loop -------------------------------------------------------
    for (int t = 0; t <= T_STEPS; ++t) {
        if (t > 0) {
            if (tid < NWG) {
                unsigned spins = 0;
                for (;;) {
                    if (__hip_atomic_load(&tag[tid], __ATOMIC_RELAXED,
                                          __HIP_MEMORY_SCOPE_AGENT) >= (unsigned)t) break;
                    __builtin_amdgcn_s_sleep(1);
                    ++spins;
                    if ((spins & 2047u) == 0u) {   // safety valve: never hangs forever
                        if (__hip_atomic_load(&tag[63], __ATOMIC_RELAXED,
                                              __HIP_MEMORY_SCOPE_AGENT) != 0u) break;
                        if (spins >= (1u << 17)) {
                            __hip_atomic_store(&tag[63], 1u, __ATOMIC_RELAXED,
                                               __HIP_MEMORY_SCOPE_AGENT);
                            break;
                        }
                    }
                }
            }
            __syncthreads();
            __threadfence();   // acquire: invalidate stale cached ring lines
        }

        const bool active = isL1 ? (t < T_STEPS) : (t >= 1);
        if (active) {
            // primary operand: h1[t-1] (t==0 reads slot 3 == zeros)
            const float* prim = h1ring + ((t - 1) & 3) * 512 + ct * 16;
            float4 p0 = *(const float4*)(prim + 0);
            float4 p1 = *(const float4*)(prim + 4);
            float4 p2 = *(const float4*)(prim + 8);
            float4 p3 = *(const float4*)(prim + 12);
            float v[16];
            v[ 0] = p0.x; v[ 1] = p0.y; v[ 2] = p0.z; v[ 3] = p0.w;
            v[ 4] = p1.x; v[ 5] = p1.y; v[ 6] = p1.z; v[ 7] = p1.w;
            v[ 8] = p2.x; v[ 9] = p2.y; v[10] = p2.z; v[11] = p2.w;
            v[12] = p3.x; v[13] = p3.y; v[14] = p3.z; v[15] = p3.w;

            float vb[4];
            if (isL1) {
                vb[0] = vx.x; vb[1] = vx.y; vb[2] = vx.z; vb[3] = vx.w;
            } else {
                // secondary: h2[tau-1], tau = t-1 (tau==0 reads slot 3 == zeros)
                const float* sec = h2ring + ((t - 2) & 3) * 128 + ct * 4;
                float4 s4 = *(const float4*)sec;
                vb[0] = s4.x; vb[1] = s4.y; vb[2] = s4.z; vb[3] = s4.w;
            }

            float acc[4] = {0.f, 0.f, 0.f, 0.f};
#pragma unroll
            for (int q = 0; q < 4; ++q) {
#pragma unroll
                for (int j = 0; j < 16; ++j) acc[q] = fmaf(wA[q][j], v[j], acc[q]);
#pragma unroll
                for (int j = 0; j < 4; ++j)  acc[q] = fmaf(wB[q][j], vb[j], acc[q]);
            }

            // prefetch next x row while reducing (off critical path)
            if (isL1) {
                const int tn = (t + 1 < T_STEPS) ? (t + 1) : (T_STEPS - 1);
                vx = *(const float4*)(x + (size_t)tn * 128 + ct * 4);
            }

            // ---- reduce over ct (32 lanes) via LDS transpose + shfl ------
#pragma unroll
            for (int q = 0; q < 4; ++q) part[rt * 4 + q][ct] = acc[q];
            __syncthreads();
            {
                const int r = tid >> 3;      // 0..63
                const int o = tid & 7;       // 0..7
                float s = part[r][o * 4 + 0] + part[r][o * 4 + 1]
                        + part[r][o * 4 + 2] + part[r][o * 4 + 3];
                s += __shfl_down(s, 4);
                s += __shfl_down(s, 2);
                s += __shfl_down(s, 1);
                if (o == 0) gs[r] = s;
            }
            __syncthreads();

            // ---- activations, state update, publish (threads 0..15) ------
            if (tid < 16) {
                const float gi = gs[ 0 + tid] + bias[0];
                const float gf = gs[16 + tid] + bias[1];
                const float gg = gs[32 + tid] + bias[2];
                const float go = gs[48 + tid] + bias[3];
                const float ii = sigm(gi);
                const float ff = sigm(gf);
                const float g2 = tanh_fast(gg);
                const float oo = sigm(go);
                cst = ff * cst + ii * g2;
                const float h = oo * tanh_fast(cst);
                if (isL1) {
                    h1ring[(t & 3) * 512 + hb + tid] = h;
                } else {
                    const int tau = t - 1;
                    h2ring[(tau & 3) * 128 + hb + tid] = h;
                    out[(size_t)tau * 128 + hb + tid] = h;
                }
            }
            __threadfence();   // release: flush ring stores before tagging
        }

        if (t < T_STEPS) {
            __syncthreads();   // ensure wave-0 stores+fence done before tag
            if (tid == 0)
                __hip_atomic_store(&tag[w], (unsigned)(t + 1), __ATOMIC_RELAXED,
                                   __HIP_MEMORY_SCOPE_AGENT);
        }
    }
}

extern "C" void kernel_launch(void* const* d_in, const int* in_sizes, int n_in,
                              void* d_out, int out_size, void* d_ws, size_t ws_size,
                              hipStream_t stream)
{
    const float* x    = (const float*)d_in[0];
    const float* Wih1 = (const float*)d_in[1];
    const float* Whh1 = (const float*)d_in[2];
    const float* bih1 = (const float*)d_in[3];
    const float* bhh1 = (const float*)d_in[4];
    const float* Wih2 = (const float*)d_in[5];
    const float* Whh2 = (const float*)d_in[6];
    const float* bih2 = (const float*)d_in[7];
    const float* bhh2 = (const float*)d_in[8];
    unsigned int* ws  = (unsigned int*)d_ws;

    hipLaunchKernelGGL(lstm_init, dim3(16), dim3(256), 0, stream, ws);
    hipLaunchKernelGGL(lstm_persist, dim3(NWG), dim3(BLK), 0, stream,
                       x, Wih1, Whh1, bih1, bhh1, Wih2, Whh2, bih2, bhh2,
                       (float*)d_out, ws);
}

// Round 2
// 147588.489 us; speedup vs baseline: 2.5797x; 2.5797x over previous
//
#include <hip/hip_runtime.h>
#include <math.h>

// ---------------------------------------------------------------------------
// 2-layer LSTM, batch=1, T=32768, I=128, H=512  (PyTorch gate order i,f,g,o)
//
// ONE persistent kernel, 40 WGs x 512 threads.
//   WG 0..31  : layer-1. WG w owns h1[w*16 .. w*16+16) -> 64 gate rows.
//   WG 32..39 : layer-2, runs 1 step behind (tau = t-1).
// Per-lane weights in VGPRs: 4 rows x (16 primary + 4 secondary) = 80 f32.
//
// Cross-WG communication: NO fences. Every shared word is accessed with
// agent-scope relaxed atomics (-> sc1, bypasses per-XCD L1/L2, coherent at
// L3). Producer protocol: store 16 data words (sc1) -> s_waitcnt vmcnt(0)
// -> store seq word (sc1). Consumer protocol: poll seq (sc1) until it
// equals the expected step, THEN load data (sc1). Wait-then-load is
// race-free: the data stores were ACKed at the coherence point before the
// seq store was even issued.
//
// Ring depth 4 + lazy progress tags (threshold t-2, 3 steps of slack) make
// slot overwrite safe without any step-lockstep barrier.
// ---------------------------------------------------------------------------

#define T_STEPS 32768
#define NL1     32
#define NL2     8
#define NWG     40
#define BLK     512

// ws layout (u32 words):
//  [0..63]        progress tags (40 used), [63] = abort flag
//  [256..4351]    h1 entries: 4 slots x 32 wg x 32 words (data[0..15], seq@16)
//  [4352..5375]   h2 entries: 4 slots x  8 wg x 32 words
#define H1_OFF   256
#define H2_OFF   (H1_OFF + 4 * 32 * 32)
#define WS_WORDS 6144

__device__ __forceinline__ float sigm(float x) { return 1.0f / (1.0f + __expf(-x)); }
__device__ __forceinline__ float tanh_fast(float x) { return 1.0f - 2.0f / (__expf(2.0f * x) + 1.0f); }

__device__ __forceinline__ unsigned ld_u32(const unsigned* p) {
    return __hip_atomic_load(p, __ATOMIC_RELAXED, __HIP_MEMORY_SCOPE_AGENT);
}
__device__ __forceinline__ unsigned long long ld_u64(const unsigned long long* p) {
    return __hip_atomic_load(p, __ATOMIC_RELAXED, __HIP_MEMORY_SCOPE_AGENT);
}
__device__ __forceinline__ void st_u32(unsigned* p, unsigned v) {
    __hip_atomic_store(p, v, __ATOMIC_RELAXED, __HIP_MEMORY_SCOPE_AGENT);
}

// poll until *p == want (1) or *p >= want (0). returns 0 ok, 1 aborted.
template <int EQ>
__device__ __forceinline__ int poll_word(const unsigned* p, unsigned want, unsigned* abortf) {
    unsigned spins = 0;
    for (;;) {
        unsigned v = ld_u32(p);
        if (EQ ? (v == want) : ((int)v >= (int)want)) return 0;
        if ((++spins & 1023u) == 0u) {
            if (ld_u32(abortf) != 0u) return 1;
            if (spins >= (1u << 19)) { st_u32(abortf, 1u); return 1; }
        }
    }
}

__global__ void lstm_init(unsigned int* ws)
{
    int i = blockIdx.x * blockDim.x + threadIdx.x;
    if (i < WS_WORDS) ws[i] = 0u;
}

__global__ __launch_bounds__(BLK, 1) void lstm_persist(
    const float* __restrict__ x,      // [32768][128]
    const float* __restrict__ Wih1,   // [2048][128]
    const float* __restrict__ Whh1,   // [2048][512]
    const float* __restrict__ bih1,
    const float* __restrict__ bhh1,
    const float* __restrict__ Wih2,   // [512][512]
    const float* __restrict__ Whh2,   // [512][128]
    const float* __restrict__ bih2,
    const float* __restrict__ bhh2,
    float* __restrict__ out,          // [32768][128]
    unsigned int* ws)
{
    const int w     = blockIdx.x;
    const bool isL1 = (w < NL1);
    const int tid   = threadIdx.x;
    const int rt    = tid >> 5;   // 0..15 row-tile (4 rows each)
    const int ct    = tid & 31;   // 0..31 col-tile

    unsigned* tag   = ws;                 // [40], [63]=abort
    unsigned* abf   = ws + 63;
    unsigned* h1e   = ws + H1_OFF;        // entries: ((slot*32+wg)*32)
    unsigned* h2e   = ws + H2_OFF;        // entries: ((slot*8 +wg)*32)

    __shared__ float part[64][33];
    __shared__ float gs[64];

    const int hb = (isL1 ? w : (w - NL1)) * 16;
    const int Hd = isL1 ? 512 : 128;
    const float* WA = isL1 ? Whh1 : Wih2;   // [4*Hd][512]
    const float* WB = isL1 ? Wih1 : Whh2;   // [4*Hd][128]

    // ---- weights into registers (once) -----------------------------------
    float wA[4][16];
    float wB[4][4];
#pragma unroll
    for (int q = 0; q < 4; ++q) {
        const int rl   = rt * 4 + q;
        const int g    = rl >> 4;
        const int hl   = rl & 15;
        const int grow = g * Hd + hb + hl;
        const float4* pa = (const float4*)(WA + (size_t)grow * 512 + ct * 16);
#pragma unroll
        for (int jj = 0; jj < 4; ++jj) {
            float4 t4 = pa[jj];
            wA[q][jj * 4 + 0] = t4.x; wA[q][jj * 4 + 1] = t4.y;
            wA[q][jj * 4 + 2] = t4.z; wA[q][jj * 4 + 3] = t4.w;
        }
        float4 tb = *(const float4*)(WB + (size_t)grow * 128 + ct * 4);
        wB[q][0] = tb.x; wB[q][1] = tb.y; wB[q][2] = tb.z; wB[q][3] = tb.w;
    }

    float bias[4] = {0.f, 0.f, 0.f, 0.f};
    float cst = 0.0f;
    if (tid < 16) {
        const float* bi = isL1 ? bih1 : bih2;
        const float* bh = isL1 ? bhh1 : bhh2;
#pragma unroll
        for (int g = 0; g < 4; ++g)
            bias[g] = bi[g * Hd + hb + tid] + bh[g * Hd + hb + tid];
    }

    float4 vx = make_float4(0.f, 0.f, 0.f, 0.f);
    if (isL1) vx = *(const float4*)(x + ct * 4);   // x[0]

    // ---- time loop -------------------------------------------------------
    for (int t = 0; t <= T_STEPS; ++t) {
        // lazy anti-overwrite check: writers of step t must know all readers
        // passed step t-3 (tag >= t-2). 3 steps of slack -> never blocks.
        if (t >= 2 && tid < NWG) {
            if (poll_word<0>(&tag[tid], (unsigned)(t - 2), abf)) break;
        }

        const bool active = isL1 ? (t < T_STEPS) : (t >= 1);
        if (active) {
            // ---- wait-then-load primary operand h1[t-1] ------------------
            // producer WG ct's entry, slot (t-1)&3, expected seq == t
            const unsigned eA = (unsigned)((((t - 1) & 3) * 32 + ct) * 32);
            if (poll_word<1>(h1e + eA + 16, (unsigned)t, abf)) break;
            const unsigned long long* pdA = (const unsigned long long*)(h1e + eA);
            float v[16];
#pragma unroll
            for (int j = 0; j < 8; ++j) {
                unsigned long long u = ld_u64(pdA + j);
                v[2 * j]     = __uint_as_float((unsigned)(u & 0xffffffffull));
                v[2 * j + 1] = __uint_as_float((unsigned)(u >> 32));
            }

            float vb[4];
            if (isL1) {
                vb[0] = vx.x; vb[1] = vx.y; vb[2] = vx.z; vb[3] = vx.w;
            } else {
                // h2[t-2]: producer wg2 = ct>>2, slot (t-2)&3, seq == t-1
                const unsigned eB = (unsigned)((((t - 2) & 3) * 8 + (ct >> 2)) * 32);
                if (poll_word<1>(h2e + eB + 16, (unsigned)(t - 1), abf)) break;
                const unsigned long long* pdB =
                    (const unsigned long long*)(h2e + eB) + (ct & 3) * 2;
                unsigned long long u0 = ld_u64(pdB + 0);
                unsigned long long u1 = ld_u64(pdB + 1);
                vb[0] = __uint_as_float((unsigned)(u0 & 0xffffffffull));
                vb[1] = __uint_as_float((unsigned)(u0 >> 32));
                vb[2] = __uint_as_float((unsigned)(u1 & 0xffffffffull));
                vb[3] = __uint_as_float((unsigned)(u1 >> 32));
            }

            float acc[4] = {0.f, 0.f, 0.f, 0.f};
#pragma unroll
            for (int q = 0; q < 4; ++q) {
#pragma unroll
                for (int j = 0; j < 16; ++j) acc[q] = fmaf(wA[q][j], v[j], acc[q]);
#pragma unroll
                for (int j = 0; j < 4; ++j)  acc[q] = fmaf(wB[q][j], vb[j], acc[q]);
            }

            // prefetch next x row (plain cached load, read-only data)
            if (isL1) {
                const int tn = (t + 1 < T_STEPS) ? (t + 1) : (T_STEPS - 1);
                vx = *(const float4*)(x + (size_t)tn * 128 + ct * 4);
            }

            // ---- reduce over ct via LDS transpose + shfl -----------------
#pragma unroll
            for (int q = 0; q < 4; ++q) part[rt * 4 + q][ct] = acc[q];
            __syncthreads();

            // reads of this step's ring data are all consumed -> publish progress
            if (tid == 0) st_u32(&tag[w], (unsigned)(t + 1));

            {
                const int r = tid >> 3;
                const int o = tid & 7;
                float s = part[r][o * 4 + 0] + part[r][o * 4 + 1]
                        + part[r][o * 4 + 2] + part[r][o * 4 + 3];
                s += __shfl_down(s, 4);
                s += __shfl_down(s, 2);
                s += __shfl_down(s, 1);
                if (o == 0) gs[r] = s;
            }
            __syncthreads();

            // ---- activations + publish (wave 0 only) ---------------------
            if (tid < 16) {
                const float gi = gs[ 0 + tid] + bias[0];
                const float gf = gs[16 + tid] + bias[1];
                const float gg = gs[32 + tid] + bias[2];
                const float go = gs[48 + tid] + bias[3];
                const float ii = sigm(gi);
                const float ff = sigm(gf);
                const float g2 = tanh_fast(gg);
                const float oo = sigm(go);
                cst = ff * cst + ii * g2;
                const float h = oo * tanh_fast(cst);
                if (isL1) {
                    const unsigned e = (unsigned)(((t & 3) * 32 + w) * 32);
                    st_u32(h1e + e + tid, __float_as_uint(h));
                } else {
                    const int tau = t - 1;
                    const unsigned e = (unsigned)((((tau & 3) * 8 + (w - NL1)) * 32));
                    st_u32(h2e + e + tid, __float_as_uint(h));
                    out[(size_t)tau * 128 + hb + tid] = h;
                }
            }
            if (tid < 64) {
                // data stores ACK at L3 before seq store issues
                asm volatile("s_waitcnt vmcnt(0)" ::: "memory");
                if (tid == 0) {
                    if (isL1) {
                        const unsigned e = (unsigned)(((t & 3) * 32 + w) * 32);
                        st_u32(h1e + e + 16, (unsigned)(t + 1));
                    } else {
                        const int tau = t - 1;
                        const unsigned e = (unsigned)(((tau & 3) * 8 + (w - NL1)) * 32);
                        st_u32(h2e + e + 16, (unsigned)(tau + 1));
                    }
                }
            }
        }
    }
}

extern "C" void kernel_launch(void* const* d_in, const int* in_sizes, int n_in,
                              void* d_out, int out_size, void* d_ws, size_t ws_size,
                              hipStream_t stream)
{
    const float* x    = (const float*)d_in[0];
    const float* Wih1 = (const float*)d_in[1];
    const float* Whh1 = (const float*)d_in[2];
    const float* bih1 = (const float*)d_in[3];
    const float* bhh1 = (const float*)d_in[4];
    const float* Wih2 = (const float*)d_in[5];
    const float* Whh2 = (const float*)d_in[6];
    const float* bih2 = (const float*)d_in[7];
    const float* bhh2 = (const float*)d_in[8];
    unsigned int* ws  = (unsigned int*)d_ws;

    hipLaunchKernelGGL(lstm_init, dim3(24), dim3(256), 0, stream, ws);
    hipLaunchKernelGGL(lstm_persist, dim3(NWG), dim3(BLK), 0, stream,
                       x, Wih1, Whh1, bih1, bhh1, Wih2, Whh2, bih2, bhh2,
                       (float*)d_out, ws);
}

// Round 3
// 98615.314 us; speedup vs baseline: 3.8608x; 1.4966x over previous
//
#include <hip/hip_runtime.h>
#include <math.h>

// ---------------------------------------------------------------------------
// 2-layer LSTM, batch=1, T=32768, I=128, H=512  (PyTorch gate order i,f,g,o)
//
// ONE persistent kernel, 40 WGs x 512 threads.
//   WG 0..31  : layer-1. WG w owns h1[w*16 .. w*16+16).
//   WG 32..39 : layer-2, runs 1 step behind (tau = t-1).
//
// Cross-WG handoff: each h value is published as ONE 64-bit relaxed
// agent-scope atomic word: (tag << 32) | f32_bits(h). Atomic per-element ->
// no producer fence/ack/seq chain, and the consumer's poll loop IS the data
// load. Rings are depth-4; a lazy per-WG progress tag (>= t-2) guards slot
// overwrite with exactly-tight 3-step slack.
//
// Per WG: waves 0/1 poll+stage h1 (512 pairs) into padded LDS; wave 2 does
// h2 (128 pairs, layer-2 only); ONE __syncthreads per step; operand buffers
// double-buffered by t&1. Row mapping (gate = q, h-index = rt) keeps all 4
// gates of an h-index inside one half-wave: reduction = 5 shfl_xor steps,
// activations replicated across the half-wave, leader lane publishes.
// ---------------------------------------------------------------------------

#define T_STEPS 32768
#define NL1     32
#define NWG     40
#define BLK     512

// ws u32 layout:
//  [0..63]        progress tags (40 used), [63] = global abort flag
//  [128..4223]    h1 pairs u64[4][512]
//  [4224..5247]   h2 pairs u64[4][128]
#define H1P_OFF  128
#define H2P_OFF  (H1P_OFF + 4 * 512 * 2)
#define WS_WORDS 6144

__device__ __forceinline__ float sigm(float x) { return 1.0f / (1.0f + __expf(-x)); }
__device__ __forceinline__ float tanh_fast(float x) { return 1.0f - 2.0f / (__expf(2.0f * x) + 1.0f); }

__device__ __forceinline__ unsigned ld_u32(const unsigned* p) {
    return __hip_atomic_load(p, __ATOMIC_RELAXED, __HIP_MEMORY_SCOPE_AGENT);
}
__device__ __forceinline__ void st_u32(unsigned* p, unsigned v) {
    __hip_atomic_store(p, v, __ATOMIC_RELAXED, __HIP_MEMORY_SCOPE_AGENT);
}
__device__ __forceinline__ unsigned long long ld_u64(const unsigned long long* p) {
    return __hip_atomic_load(p, __ATOMIC_RELAXED, __HIP_MEMORY_SCOPE_AGENT);
}
__device__ __forceinline__ void st_u64(unsigned long long* p, unsigned long long v) {
    __hip_atomic_store(p, v, __ATOMIC_RELAXED, __HIP_MEMORY_SCOPE_AGENT);
}

__global__ void lstm_init(unsigned int* ws)
{
    int i = blockIdx.x * blockDim.x + threadIdx.x;
    if (i < WS_WORDS) ws[i] = 0u;
}

__global__ __launch_bounds__(BLK, 1) void lstm_persist(
    const float* __restrict__ x,      // [32768][128]
    const float* __restrict__ Wih1,   // [2048][128]
    const float* __restrict__ Whh1,   // [2048][512]
    const float* __restrict__ bih1,
    const float* __restrict__ bhh1,
    const float* __restrict__ Wih2,   // [512][512]
    const float* __restrict__ Whh2,   // [512][128]
    const float* __restrict__ bih2,
    const float* __restrict__ bhh2,
    float* __restrict__ out,          // [32768][128]
    unsigned int* ws)
{
    const int w     = blockIdx.x;
    const bool isL1 = (w < NL1);
    const int tid   = threadIdx.x;
    const int rt    = tid >> 5;     // 0..15 : h-index within WG (4 gate rows)
    const int ct    = tid & 31;     // 0..31 : col-tile (16 primary + 4 secondary)
    const int wave  = tid >> 6;     // 0..7
    const int lane  = tid & 63;     // 0..63

    unsigned* tag            = ws;
    unsigned* abf            = ws + 63;
    unsigned long long* h1p  = (unsigned long long*)(ws + H1P_OFF);  // [4][512]
    unsigned long long* h2p  = (unsigned long long*)(ws + H2P_OFF);  // [4][128]

    __shared__ __align__(16) float h1buf[2][32 * 20];   // padded: entry stride 20
    __shared__ __align__(16) float h2buf[2][8 * 20];
    __shared__ unsigned s_ab;

    if (tid == 0) s_ab = 0u;

    const int hb = (isL1 ? w : (w - NL1)) * 16;
    const int Hd = isL1 ? 512 : 128;
    const float* WA = isL1 ? Whh1 : Wih2;   // [4*Hd][512]
    const float* WB = isL1 ? Wih1 : Whh2;   // [4*Hd][128]

    // ---- weights (4 gate rows of h-index rt, col slices ct) --------------
    float wAr[4][16];
    float wBr[4][4];
    float bias[4];
#pragma unroll
    for (int q = 0; q < 4; ++q) {
        const int grow = q * Hd + hb + rt;
        const float4* pa = (const float4*)(WA + (size_t)grow * 512 + ct * 16);
#pragma unroll
        for (int jj = 0; jj < 4; ++jj) {
            float4 t4 = pa[jj];
            wAr[q][jj * 4 + 0] = t4.x; wAr[q][jj * 4 + 1] = t4.y;
            wAr[q][jj * 4 + 2] = t4.z; wAr[q][jj * 4 + 3] = t4.w;
        }
        float4 tb = *(const float4*)(WB + (size_t)grow * 128 + ct * 4);
        wBr[q][0] = tb.x; wBr[q][1] = tb.y; wBr[q][2] = tb.z; wBr[q][3] = tb.w;
        const float* bi = isL1 ? bih1 : bih2;
        const float* bh = isL1 ? bhh1 : bhh2;
        bias[q] = bi[grow] + bh[grow];
    }

    float cst = 0.0f;
    float4 vx = make_float4(0.f, 0.f, 0.f, 0.f);
    if (isL1) vx = *(const float4*)(x + ct * 4);   // x[0]

    __syncthreads();   // s_ab visible

    // ---- time loop -------------------------------------------------------
    for (int t = 0; t <= T_STEPS; ++t) {
        const bool active = isL1 ? (t < T_STEPS) : (t >= 1);

        if (active && wave == 0) {
            // overwrite guard: all readers must have passed step t-3
            if (t >= 2) {
                unsigned spins = 0;
                for (;;) {
                    int ok = (lane >= NWG) ||
                             ((int)ld_u32(&tag[lane < NWG ? lane : 0]) >= (int)(t - 2));
                    if (__all(ok)) break;
                    if ((++spins & 255u) == 0u) {
                        if (ld_u32(abf) != 0u) { if (lane == 0) s_ab = 1u; break; }
                        if (spins >= (1u << 19)) {
                            st_u32(abf, 1u); if (lane == 0) s_ab = 1u; break;
                        }
                    }
                }
            }
        }
        if (active && wave < 2) {
            // ---- poll h1 pairs (operand h1[t-1], tag == t), stage to LDS --
            const unsigned long long* base =
                h1p + (size_t)((t - 1) & 3) * 512 + wave * 256 + lane * 4;
            unsigned long long a0, a1, a2, a3;
            unsigned spins = 0;
            for (;;) {
                a0 = ld_u64(base + 0); a1 = ld_u64(base + 1);
                a2 = ld_u64(base + 2); a3 = ld_u64(base + 3);
                int ok = ((unsigned)(a0 >> 32) == (unsigned)t) &
                         ((unsigned)(a1 >> 32) == (unsigned)t) &
                         ((unsigned)(a2 >> 32) == (unsigned)t) &
                         ((unsigned)(a3 >> 32) == (unsigned)t);
                if (__all(ok)) break;
                if ((++spins & 255u) == 0u) {
                    if (ld_u32(abf) != 0u) { if (lane == 0) s_ab = 1u; break; }
                    if (spins >= (1u << 19)) {
                        st_u32(abf, 1u); if (lane == 0) s_ab = 1u; break;
                    }
                }
            }
            const int e = wave * 16 + (lane >> 2);          // entry 0..31
            float4 vals;
            vals.x = __uint_as_float((unsigned)a0);
            vals.y = __uint_as_float((unsigned)a1);
            vals.z = __uint_as_float((unsigned)a2);
            vals.w = __uint_as_float((unsigned)a3);
            *(float4*)&h1buf[t & 1][e * 20 + (lane & 3) * 4] = vals;
        }
        if (active && wave == 2 && !isL1) {
            // ---- poll h2 pairs (operand h2[t-2], tag == t-1) --------------
            const unsigned long long* base =
                h2p + (size_t)((t - 2) & 3) * 128 + lane * 2;
            unsigned long long a0, a1;
            unsigned spins = 0;
            for (;;) {
                a0 = ld_u64(base + 0); a1 = ld_u64(base + 1);
                int ok = ((unsigned)(a0 >> 32) == (unsigned)(t - 1)) &
                         ((unsigned)(a1 >> 32) == (unsigned)(t - 1));
                if (__all(ok)) break;
                if ((++spins & 255u) == 0u) {
                    if (ld_u32(abf) != 0u) { if (lane == 0) s_ab = 1u; break; }
                    if (spins >= (1u << 19)) {
                        st_u32(abf, 1u); if (lane == 0) s_ab = 1u; break;
                    }
                }
            }
            const int e = lane >> 3;                         // entry 0..7
            float2 vals;
            vals.x = __uint_as_float((unsigned)a0);
            vals.y = __uint_as_float((unsigned)a1);
            *(float2*)&h2buf[t & 1][e * 20 + (lane & 7) * 2] = vals;
        }

        __syncthreads();
        if (s_ab) break;

        if (active) {
            if (tid == 0) st_u32(&tag[w], (unsigned)(t + 1));  // done reading step-t inputs

            // ---- operands from LDS ---------------------------------------
            const float* hb1 = &h1buf[t & 1][ct * 20];
            float4 p0 = *(const float4*)(hb1 + 0);
            float4 p1 = *(const float4*)(hb1 + 4);
            float4 p2 = *(const float4*)(hb1 + 8);
            float4 p3 = *(const float4*)(hb1 + 12);
            float v[16] = { p0.x, p0.y, p0.z, p0.w,  p1.x, p1.y, p1.z, p1.w,
                            p2.x, p2.y, p2.z, p2.w,  p3.x, p3.y, p3.z, p3.w };
            float vb[4];
            if (isL1) {
                vb[0] = vx.x; vb[1] = vx.y; vb[2] = vx.z; vb[3] = vx.w;
            } else {
                float4 s4 = *(const float4*)&h2buf[t & 1][(ct >> 2) * 20 + (ct & 3) * 4];
                vb[0] = s4.x; vb[1] = s4.y; vb[2] = s4.z; vb[3] = s4.w;
            }

            float acc[4] = {0.f, 0.f, 0.f, 0.f};
#pragma unroll
            for (int q = 0; q < 4; ++q) {
#pragma unroll
                for (int j = 0; j < 16; ++j) acc[q] = fmaf(wAr[q][j], v[j], acc[q]);
#pragma unroll
                for (int j = 0; j < 4; ++j)  acc[q] = fmaf(wBr[q][j], vb[j], acc[q]);
            }

            // prefetch next x row (off critical path)
            if (isL1) {
                const int tn = (t + 1 < T_STEPS) ? (t + 1) : (T_STEPS - 1);
                vx = *(const float4*)(x + (size_t)tn * 128 + ct * 4);
            }

            // ---- reduce over 32 col-lanes (within half-wave) -------------
#pragma unroll
            for (int m = 16; m >= 1; m >>= 1) {
#pragma unroll
                for (int q = 0; q < 4; ++q)
                    acc[q] += __shfl_xor(acc[q], m, 64);
            }

            // ---- activations (replicated across half-wave, identical FP) -
            const float ii = sigm(acc[0] + bias[0]);
            const float ff = sigm(acc[1] + bias[1]);
            const float g2 = tanh_fast(acc[2] + bias[2]);
            const float oo = sigm(acc[3] + bias[3]);
            cst = ff * cst + ii * g2;
            const float h = oo * tanh_fast(cst);

            // ---- publish (half-wave leader) ------------------------------
            if (ct == 0) {
                if (isL1) {
                    const unsigned long long pair =
                        ((unsigned long long)(unsigned)(t + 1) << 32) |
                        (unsigned long long)__float_as_uint(h);
                    st_u64(&h1p[(size_t)(t & 3) * 512 + w * 16 + rt], pair);
                } else {
                    const int tau = t - 1;
                    const unsigned long long pair =
                        ((unsigned long long)(unsigned)t << 32) |
                        (unsigned long long)__float_as_uint(h);
                    st_u64(&h2p[(size_t)(tau & 3) * 128 + (w - NL1) * 16 + rt], pair);
                    out[(size_t)tau * 128 + hb + rt] = h;
                }
            }
        }
    }
}

extern "C" void kernel_launch(void* const* d_in, const int* in_sizes, int n_in,
                              void* d_out, int out_size, void* d_ws, size_t ws_size,
                              hipStream_t stream)
{
    const float* x    = (const float*)d_in[0];
    const float* Wih1 = (const float*)d_in[1];
    const float* Whh1 = (const float*)d_in[2];
    const float* bih1 = (const float*)d_in[3];
    const float* bhh1 = (const float*)d_in[4];
    const float* Wih2 = (const float*)d_in[5];
    const float* Whh2 = (const float*)d_in[6];
    const float* bih2 = (const float*)d_in[7];
    const float* bhh2 = (const float*)d_in[8];
    unsigned int* ws  = (unsigned int*)d_ws;

    hipLaunchKernelGGL(lstm_init, dim3(32), dim3(256), 0, stream, ws);
    hipLaunchKernelGGL(lstm_persist, dim3(NWG), dim3(BLK), 0, stream,
                       x, Wih1, Whh1, bih1, bhh1, Wih2, Whh2, bih2, bhh2,
                       (float*)d_out, ws);
}

// Round 6
// 87845.679 us; speedup vs baseline: 4.3341x; 1.1226x over previous
//
#include <hip/hip_runtime.h>
#include <math.h>

// ---------------------------------------------------------------------------
// 2-layer LSTM, batch=1, T=32768, I=128, H=512  (PyTorch gate order i,f,g,o)
//
// XCD-local persistent design WITH CORRECTNESS FALLBACK.
//   Launch 192 WGs x 512 thr; workers are blockIdx%8==0 (24 WGs, role=bid>>3)
//   -> all on XCD 0 under the documented round-robin blockIdx->XCD mapping.
//   WG 0..15  : layer-1, role k owns h1[k*32 .. k*32+32)
//   WG 16..23 : layer-2, role j-16 owns h2[(j-16)*16 ..+16), 1 step behind.
//
// Handoff: each h value is (tag<<32)|f32bits, published to TWO rings:
//   fast ring: sc0 store/load  (stays in the XCD's shared L2, ~300cy RT)
//   slow ring: sc1 store/load  (device-coherent at L3, ~1500cy RT — PROVEN
//              protocol from rounds 2-3)
// Consumers spin on the fast ring; every 8th iter they read the slow ring
// and per-element merge. If the XCD mapping or sc0-coherence assumption is
// wrong, the slow ring still delivers -> correct output, just slower.
// Depth-8 rings; lazy overwrite guard (readers' tags >= n-6) in idle wave 3,
// off the critical path. One __syncthreads per step.
// ---------------------------------------------------------------------------

#define T_STEPS 32768
#define L1WG    16
#define NWG     24
#define BLK     512
#define GRID    192
#define RD      8

// ws u32 layout
#define ABT_OFF  9
#define TAG_OFF  32                        // tags[24]
#define H1F_OFF  1024                      // u64[RD][512] fast  (8192 u32)
#define H1S_OFF  (H1F_OFF + RD * 512 * 2)  // u64[RD][512] slow
#define H2F_OFF  (H1S_OFF + RD * 512 * 2)  // u64[RD][128] fast  (2048 u32)
#define H2S_OFF  (H2F_OFF + RD * 128 * 2)  // u64[RD][128] slow
#define WS_WORDS (H2S_OFF + RD * 128 * 2)  // 21504 u32 = 86 KB

typedef unsigned int uint4v __attribute__((ext_vector_type(4)));

__device__ __forceinline__ float sigm(float x) { return 1.0f / (1.0f + __expf(-x)); }
__device__ __forceinline__ float tanh_fast(float x) { return 1.0f - 2.0f / (__expf(2.0f * x) + 1.0f); }

// ---- scoped access helpers ------------------------------------------------
__device__ __forceinline__ unsigned ld_u32_sc1(const unsigned* p) {
    unsigned r;
    asm volatile("global_load_dword %0, %1, off sc1\n\ts_waitcnt vmcnt(0)"
                 : "=v"(r) : "v"(p) : "memory");
    return r;
}
__device__ __forceinline__ void st_u32_sc1(unsigned* p, unsigned v) {
    asm volatile("global_store_dword %0, %1, off sc1" :: "v"(p), "v"(v) : "memory");
}
__device__ __forceinline__ void st_u64_sc0(unsigned long long* p, unsigned long long v) {
    asm volatile("global_store_dwordx2 %0, %1, off sc0" :: "v"(p), "v"(v) : "memory");
}
__device__ __forceinline__ void st_u64_sc1(unsigned long long* p, unsigned long long v) {
    asm volatile("global_store_dwordx2 %0, %1, off sc1" :: "v"(p), "v"(v) : "memory");
}
__device__ __forceinline__ void ld2x16_sc0(const unsigned long long* p, uint4v& A, uint4v& B) {
    asm volatile("global_load_dwordx4 %0, %2, off sc0\n\t"
                 "global_load_dwordx4 %1, %3, off sc0\n\t"
                 "s_waitcnt vmcnt(0)"
                 : "=&v"(A), "=&v"(B) : "v"(p), "v"(p + 2) : "memory");
}
__device__ __forceinline__ void ld2x16_sc1(const unsigned long long* p, uint4v& A, uint4v& B) {
    asm volatile("global_load_dwordx4 %0, %2, off sc1\n\t"
                 "global_load_dwordx4 %1, %3, off sc1\n\t"
                 "s_waitcnt vmcnt(0)"
                 : "=&v"(A), "=&v"(B) : "v"(p), "v"(p + 2) : "memory");
}
__device__ __forceinline__ void ld1x16_sc0(const unsigned long long* p, uint4v& A) {
    asm volatile("global_load_dwordx4 %0, %1, off sc0\n\ts_waitcnt vmcnt(0)"
                 : "=&v"(A) : "v"(p) : "memory");
}
__device__ __forceinline__ void ld1x16_sc1(const unsigned long long* p, uint4v& A) {
    asm volatile("global_load_dwordx4 %0, %1, off sc1\n\ts_waitcnt vmcnt(0)"
                 : "=&v"(A) : "v"(p) : "memory");
}

__global__ void lstm_init(unsigned int* ws)
{
    int i = blockIdx.x * blockDim.x + threadIdx.x;
    if (i < WS_WORDS) ws[i] = 0u;
}

__global__ __launch_bounds__(BLK) void lstm_persist(
    const float* __restrict__ x,      // [32768][128]
    const float* __restrict__ Wih1,   // [2048][128]
    const float* __restrict__ Whh1,   // [2048][512]
    const float* __restrict__ bih1,
    const float* __restrict__ bhh1,
    const float* __restrict__ Wih2,   // [512][512]
    const float* __restrict__ Whh2,   // [512][128]
    const float* __restrict__ bih2,
    const float* __restrict__ bhh2,
    float* __restrict__ out,          // [32768][128]
    unsigned int* ws)
{
    const int bid = blockIdx.x;
    if (bid & 7) return;                 // workers: blockIdx % 8 == 0 -> one XCD
    const int role = bid >> 3;           // 0..23
    if (role >= NWG) return;

    const int tid  = threadIdx.x;
    const int wave = tid >> 6;
    const int lane = tid & 63;

    __shared__ __align__(16) float h1buf[2][16 * 36];   // chunked, stride 36
    __shared__ __align__(16) float h2buf[2][8 * 20];    // entry stride 20
    __shared__ unsigned s_ab[1];

    unsigned* abf  = ws + ABT_OFF;
    unsigned* tags = ws + TAG_OFF;
    unsigned long long* h1f = (unsigned long long*)(ws + H1F_OFF);
    unsigned long long* h1s = (unsigned long long*)(ws + H1S_OFF);
    unsigned long long* h2f = (unsigned long long*)(ws + H2F_OFF);
    unsigned long long* h2s = (unsigned long long*)(ws + H2S_OFF);

    if (tid == 0) s_ab[0] = 0u;

    const bool isL1 = role < L1WG;

    if (isL1) {
        // ================= LAYER 1: 32 h-indices per WG ====================
        const int rt = tid >> 4;          // 0..31 h-index
        const int ct = tid & 15;          // 0..15 col-tile (32 prim + 8 sec)
        const int hb = role * 32;

        float wA[4][32], wB[4][8], bia[4];
#pragma unroll
        for (int q = 0; q < 4; ++q) {
            const int grow = q * 512 + hb + rt;
            const float4* pa = (const float4*)(Whh1 + (size_t)grow * 512 + ct * 32);
#pragma unroll
            for (int c = 0; c < 8; ++c) {
                float4 f = pa[c];
                wA[q][c * 4 + 0] = f.x; wA[q][c * 4 + 1] = f.y;
                wA[q][c * 4 + 2] = f.z; wA[q][c * 4 + 3] = f.w;
            }
            const float4* pb = (const float4*)(Wih1 + (size_t)grow * 128 + ct * 8);
            float4 b0 = pb[0], b1 = pb[1];
            wB[q][0] = b0.x; wB[q][1] = b0.y; wB[q][2] = b0.z; wB[q][3] = b0.w;
            wB[q][4] = b1.x; wB[q][5] = b1.y; wB[q][6] = b1.z; wB[q][7] = b1.w;
            bia[q] = bih1[grow] + bhh1[grow];
        }

        float cst = 0.0f;
        float4 vx0 = *(const float4*)(x + ct * 8);
        float4 vx1 = *(const float4*)(x + ct * 8 + 4);
        __syncthreads();   // s_ab visible

        for (int n = 0; n < T_STEPS; ++n) {
            // ---- wave 3: overwrite guard (off critical path, sc1) --------
            if (wave == 3 && n >= 7 && lane < NWG) {
                const int thr = n - 6;
                unsigned sp = 0;
                for (;;) {
                    int ok = ((int)ld_u32_sc1(&tags[lane]) >= thr);
                    if (__all(ok)) break;
                    if ((++sp & 255u) == 0u) {
                        if (ld_u32_sc1(abf) != 0u) { s_ab[0] = 1u; break; }
                        if (sp >= (1u << 21)) { st_u32_sc1(abf, 1u); s_ab[0] = 1u; break; }
                    }
                }
            }
            // ---- waves 0/1: poll+merge+stage h1[n-1] (tag == n) ----------
            if (wave < 2) {
                const size_t off = (size_t)((n - 1) & (RD - 1)) * 512 + wave * 256 + lane * 4;
                const unsigned long long* pf = h1f + off;
                const unsigned long long* ps = h1s + off;
                const unsigned e = (unsigned)n;
                uint4v A, B;
                unsigned sp = 0;
                for (;;) {
                    ld2x16_sc0(pf, A, B);
                    int ok = (A.y == e) & (A.w == e) & (B.y == e) & (B.w == e);
                    if (__all(ok)) break;
                    if ((++sp & 7u) == 0u) {
                        uint4v C, D;
                        ld2x16_sc1(ps, C, D);
                        if (A.y != e) { A.x = C.x; A.y = C.y; }
                        if (A.w != e) { A.z = C.z; A.w = C.w; }
                        if (B.y != e) { B.x = D.x; B.y = D.y; }
                        if (B.w != e) { B.z = D.z; B.w = D.w; }
                        ok = (A.y == e) & (A.w == e) & (B.y == e) & (B.w == e);
                        if (__all(ok)) break;
                        if ((sp & 2047u) == 0u) {
                            if (ld_u32_sc1(abf) != 0u) { s_ab[0] = 1u; break; }
                            if (sp >= (1u << 22)) { st_u32_sc1(abf, 1u); s_ab[0] = 1u; break; }
                        }
                    }
                }
                const int g = wave * 256 + lane * 4;
                float4 vals = make_float4(__uint_as_float(A.x), __uint_as_float(A.z),
                                          __uint_as_float(B.x), __uint_as_float(B.z));
                *(float4*)&h1buf[n & 1][(g >> 5) * 36 + (g & 31)] = vals;
            }

            __syncthreads();
            if (s_ab[0]) break;
            if (tid == 0) st_u32_sc1(&tags[role], (unsigned)(n + 1));

            // ---- compute: 4 gates x (32 prim + 8 sec) cols ---------------
            float acc0 = 0.f, acc1 = 0.f, acc2 = 0.f, acc3 = 0.f;
            const float* hv = &h1buf[n & 1][ct * 36];
#pragma unroll
            for (int c = 0; c < 8; ++c) {
                float4 h4 = *(const float4*)(hv + c * 4);
                acc0 = fmaf(wA[0][c*4+0], h4.x, acc0); acc0 = fmaf(wA[0][c*4+1], h4.y, acc0);
                acc0 = fmaf(wA[0][c*4+2], h4.z, acc0); acc0 = fmaf(wA[0][c*4+3], h4.w, acc0);
                acc1 = fmaf(wA[1][c*4+0], h4.x, acc1); acc1 = fmaf(wA[1][c*4+1], h4.y, acc1);
                acc1 = fmaf(wA[1][c*4+2], h4.z, acc1); acc1 = fmaf(wA[1][c*4+3], h4.w, acc1);
                acc2 = fmaf(wA[2][c*4+0], h4.x, acc2); acc2 = fmaf(wA[2][c*4+1], h4.y, acc2);
                acc2 = fmaf(wA[2][c*4+2], h4.z, acc2); acc2 = fmaf(wA[2][c*4+3], h4.w, acc2);
                acc3 = fmaf(wA[3][c*4+0], h4.x, acc3); acc3 = fmaf(wA[3][c*4+1], h4.y, acc3);
                acc3 = fmaf(wA[3][c*4+2], h4.z, acc3); acc3 = fmaf(wA[3][c*4+3], h4.w, acc3);
            }
            {
                float sx[8] = { vx0.x, vx0.y, vx0.z, vx0.w, vx1.x, vx1.y, vx1.z, vx1.w };
#pragma unroll
                for (int j = 0; j < 8; ++j) {
                    acc0 = fmaf(wB[0][j], sx[j], acc0);
                    acc1 = fmaf(wB[1][j], sx[j], acc1);
                    acc2 = fmaf(wB[2][j], sx[j], acc2);
                    acc3 = fmaf(wB[3][j], sx[j], acc3);
                }
            }
            {   // prefetch next x row
                const int tn = (n + 1 < T_STEPS) ? (n + 1) : (T_STEPS - 1);
                vx0 = *(const float4*)(x + (size_t)tn * 128 + ct * 8);
                vx1 = *(const float4*)(x + (size_t)tn * 128 + ct * 8 + 4);
            }
#pragma unroll
            for (int m = 8; m >= 1; m >>= 1) {
                acc0 += __shfl_xor(acc0, m, 64);
                acc1 += __shfl_xor(acc1, m, 64);
                acc2 += __shfl_xor(acc2, m, 64);
                acc3 += __shfl_xor(acc3, m, 64);
            }
            const float ii = sigm(acc0 + bia[0]);
            const float ff = sigm(acc1 + bia[1]);
            const float g2 = tanh_fast(acc2 + bia[2]);
            const float oo = sigm(acc3 + bia[3]);
            cst = ff * cst + ii * g2;
            const float h = oo * tanh_fast(cst);

            if (ct == 0) {
                const unsigned long long pair =
                    ((unsigned long long)(unsigned)(n + 1) << 32) |
                    (unsigned long long)__float_as_uint(h);
                const size_t off = (size_t)(n & (RD - 1)) * 512 + hb + rt;
                st_u64_sc0(&h1f[off], pair);
                st_u64_sc1(&h1s[off], pair);
            }
        }
    } else {
        // ================= LAYER 2: 16 h-indices per WG ====================
        const int rt  = tid >> 5;         // 0..15
        const int ct  = tid & 31;         // 0..31 (16 prim + 4 sec cols)
        const int hb2 = (role - L1WG) * 16;

        float wA[4][16], wB[4][4], bia[4];
#pragma unroll
        for (int q = 0; q < 4; ++q) {
            const int grow = q * 128 + hb2 + rt;
            const float4* pa = (const float4*)(Wih2 + (size_t)grow * 512 + ct * 16);
#pragma unroll
            for (int c = 0; c < 4; ++c) {
                float4 f = pa[c];
                wA[q][c * 4 + 0] = f.x; wA[q][c * 4 + 1] = f.y;
                wA[q][c * 4 + 2] = f.z; wA[q][c * 4 + 3] = f.w;
            }
            float4 b0 = *(const float4*)(Whh2 + (size_t)grow * 128 + ct * 4);
            wB[q][0] = b0.x; wB[q][1] = b0.y; wB[q][2] = b0.z; wB[q][3] = b0.w;
            bia[q] = bih2[grow] + bhh2[grow];
        }

        float cst = 0.0f;
        __syncthreads();   // s_ab visible

        for (int n = 1; n <= T_STEPS; ++n) {
            const int tau = n - 1;
            if (wave == 3 && n >= 7 && lane < NWG) {
                const int thr = n - 6;
                unsigned sp = 0;
                for (;;) {
                    int ok = ((int)ld_u32_sc1(&tags[lane]) >= thr);
                    if (__all(ok)) break;
                    if ((++sp & 255u) == 0u) {
                        if (ld_u32_sc1(abf) != 0u) { s_ab[0] = 1u; break; }
                        if (sp >= (1u << 21)) { st_u32_sc1(abf, 1u); s_ab[0] = 1u; break; }
                    }
                }
            }
            // ---- waves 0/1: poll+merge+stage h1[tau] (tag == n) ----------
            if (wave < 2) {
                const size_t off = (size_t)(tau & (RD - 1)) * 512 + wave * 256 + lane * 4;
                const unsigned long long* pf = h1f + off;
                const unsigned long long* ps = h1s + off;
                const unsigned e = (unsigned)n;
                uint4v A, B;
                unsigned sp = 0;
                for (;;) {
                    ld2x16_sc0(pf, A, B);
                    int ok = (A.y == e) & (A.w == e) & (B.y == e) & (B.w == e);
                    if (__all(ok)) break;
                    if ((++sp & 7u) == 0u) {
                        uint4v C, D;
                        ld2x16_sc1(ps, C, D);
                        if (A.y != e) { A.x = C.x; A.y = C.y; }
                        if (A.w != e) { A.z = C.z; A.w = C.w; }
                        if (B.y != e) { B.x = D.x; B.y = D.y; }
                        if (B.w != e) { B.z = D.z; B.w = D.w; }
                        ok = (A.y == e) & (A.w == e) & (B.y == e) & (B.w == e);
                        if (__all(ok)) break;
                        if ((sp & 2047u) == 0u) {
                            if (ld_u32_sc1(abf) != 0u) { s_ab[0] = 1u; break; }
                            if (sp >= (1u << 22)) { st_u32_sc1(abf, 1u); s_ab[0] = 1u; break; }
                        }
                    }
                }
                const int g = wave * 256 + lane * 4;
                float4 vals = make_float4(__uint_as_float(A.x), __uint_as_float(A.z),
                                          __uint_as_float(B.x), __uint_as_float(B.z));
                *(float4*)&h1buf[n & 1][(g >> 5) * 36 + (g & 31)] = vals;
            }
            // ---- wave 2: poll+merge+stage h2[tau-1] (tag == tau) ---------
            if (wave == 2) {
                const size_t off = (size_t)((tau - 1) & (RD - 1)) * 128 + lane * 2;
                const unsigned long long* pf = h2f + off;
                const unsigned long long* ps = h2s + off;
                const unsigned e = (unsigned)tau;
                uint4v A;
                unsigned sp = 0;
                for (;;) {
                    ld1x16_sc0(pf, A);
                    int ok = (A.y == e) & (A.w == e);
                    if (__all(ok)) break;
                    if ((++sp & 7u) == 0u) {
                        uint4v C;
                        ld1x16_sc1(ps, C);
                        if (A.y != e) { A.x = C.x; A.y = C.y; }
                        if (A.w != e) { A.z = C.z; A.w = C.w; }
                        ok = (A.y == e) & (A.w == e);
                        if (__all(ok)) break;
                        if ((sp & 2047u) == 0u) {
                            if (ld_u32_sc1(abf) != 0u) { s_ab[0] = 1u; break; }
                            if (sp >= (1u << 22)) { st_u32_sc1(abf, 1u); s_ab[0] = 1u; break; }
                        }
                    }
                }
                const int pi = lane * 2;
                float2 v2 = make_float2(__uint_as_float(A.x), __uint_as_float(A.z));
                *(float2*)&h2buf[n & 1][(pi >> 4) * 20 + (pi & 15)] = v2;
            }

            __syncthreads();
            if (s_ab[0]) break;
            if (tid == 0) st_u32_sc1(&tags[role], (unsigned)(n + 1));

            // ---- compute: 4 gates x (16 prim + 4 sec) --------------------
            float acc0 = 0.f, acc1 = 0.f, acc2 = 0.f, acc3 = 0.f;
            const float* hv = &h1buf[n & 1][(ct >> 1) * 36 + (ct & 1) * 16];
#pragma unroll
            for (int c = 0; c < 4; ++c) {
                float4 h4 = *(const float4*)(hv + c * 4);
                acc0 = fmaf(wA[0][c*4+0], h4.x, acc0); acc0 = fmaf(wA[0][c*4+1], h4.y, acc0);
                acc0 = fmaf(wA[0][c*4+2], h4.z, acc0); acc0 = fmaf(wA[0][c*4+3], h4.w, acc0);
                acc1 = fmaf(wA[1][c*4+0], h4.x, acc1); acc1 = fmaf(wA[1][c*4+1], h4.y, acc1);
                acc1 = fmaf(wA[1][c*4+2], h4.z, acc1); acc1 = fmaf(wA[1][c*4+3], h4.w, acc1);
                acc2 = fmaf(wA[2][c*4+0], h4.x, acc2); acc2 = fmaf(wA[2][c*4+1], h4.y, acc2);
                acc2 = fmaf(wA[2][c*4+2], h4.z, acc2); acc2 = fmaf(wA[2][c*4+3], h4.w, acc2);
                acc3 = fmaf(wA[3][c*4+0], h4.x, acc3); acc3 = fmaf(wA[3][c*4+1], h4.y, acc3);
                acc3 = fmaf(wA[3][c*4+2], h4.z, acc3); acc3 = fmaf(wA[3][c*4+3], h4.w, acc3);
            }
            {
                float4 s4 = *(const float4*)&h2buf[n & 1][(ct >> 2) * 20 + (ct & 3) * 4];
                float sv[4] = { s4.x, s4.y, s4.z, s4.w };
#pragma unroll
                for (int j = 0; j < 4; ++j) {
                    acc0 = fmaf(wB[0][j], sv[j], acc0);
                    acc1 = fmaf(wB[1][j], sv[j], acc1);
                    acc2 = fmaf(wB[2][j], sv[j], acc2);
                    acc3 = fmaf(wB[3][j], sv[j], acc3);
                }
            }
#pragma unroll
            for (int m = 16; m >= 1; m >>= 1) {
                acc0 += __shfl_xor(acc0, m, 64);
                acc1 += __shfl_xor(acc1, m, 64);
                acc2 += __shfl_xor(acc2, m, 64);
                acc3 += __shfl_xor(acc3, m, 64);
            }
            const float ii = sigm(acc0 + bia[0]);
            const float ff = sigm(acc1 + bia[1]);
            const float g2 = tanh_fast(acc2 + bia[2]);
            const float oo = sigm(acc3 + bia[3]);
            cst = ff * cst + ii * g2;
            const float h = oo * tanh_fast(cst);

            if (ct == 0) {
                const unsigned long long pair =
                    ((unsigned long long)(unsigned)n << 32) |
                    (unsigned long long)__float_as_uint(h);
                const size_t off = (size_t)(tau & (RD - 1)) * 128 + hb2 + rt;
                st_u64_sc0(&h2f[off], pair);
                st_u64_sc1(&h2s[off], pair);
                out[(size_t)tau * 128 + hb2 + rt] = h;
            }
        }
    }
}

extern "C" void kernel_launch(void* const* d_in, const int* in_sizes, int n_in,
                              void* d_out, int out_size, void* d_ws, size_t ws_size,
                              hipStream_t stream)
{
    const float* x    = (const float*)d_in[0];
    const float* Wih1 = (const float*)d_in[1];
    const float* Whh1 = (const float*)d_in[2];
    const float* bih1 = (const float*)d_in[3];
    const float* bhh1 = (const float*)d_in[4];
    const float* Wih2 = (const float*)d_in[5];
    const float* Whh2 = (const float*)d_in[6];
    const float* bih2 = (const float*)d_in[7];
    const float* bhh2 = (const float*)d_in[8];
    unsigned int* ws  = (unsigned int*)d_ws;

    hipLaunchKernelGGL(lstm_init, dim3(96), dim3(256), 0, stream, ws);
    hipLaunchKernelGGL(lstm_persist, dim3(GRID), dim3(BLK), 0, stream,
                       x, Wih1, Whh1, bih1, bhh1, Wih2, Whh2, bih2, bhh2,
                       (float*)d_out, ws);
}

// Round 7
// 86826.837 us; speedup vs baseline: 4.3850x; 1.0117x over previous
//
#include <hip/hip_runtime.h>
#include <math.h>

// ---------------------------------------------------------------------------
// 2-layer LSTM, batch=1, T=32768, I=128, H=512  (PyTorch gate order i,f,g,o)
//
// XCD-local persistent design with ELECTION + CORRECTNESS FALLBACK.
//   Launch 256 WGs x 512 thr. Each WG reads its XCC_ID (s_getreg hwreg 20)
//   and takes a ticket on cnt[xcc]; the WG drawing ticket NWG-1 elects its
//   XCD via CAS; tickets 0..23 of the winning XCD are the 24 workers
//   (pigeonhole: 256 resident WGs / 8 XCDs -> some XCD reaches 24 tickets).
//   NO per-CU dedup (round-5 bug: dedup capped claimants < 24 -> deadlock).
//   WG 0..15  : layer-1, role k owns h1[k*32 .. k*32+32)
//   WG 16..23 : layer-2, role j-16 owns h2[(j-16)*16 ..+16), 1 step behind.
//
// Handoff: each h value is (tag<<32)|f32bits, published to TWO rings:
//   fast ring: sc0 store/load (XCD-shared L2, ~300cy RT when co-located)
//   slow ring: sc1 store/load (device-coherent, proven rounds 2-3-6)
// Consumers spin on the fast ring; every 8th iter merge from the slow ring.
// Any election/mapping failure degrades to slow-path speed, never to wrong
// output (round 6 proved the fallback carries correctness alone).
// Depth-8 rings. Overwrite guard (readers' tags >= n-3) runs in idle wave 3
// only every 4th step -> its sc1 RT is fully off the critical path.
// One __syncthreads per step; double-buffered LDS staging.
// ---------------------------------------------------------------------------

#define T_STEPS 32768
#define L1WG    16
#define NWG     24
#define BLK     512
#define GRID    256
#define RD      8

// ws u32 layout
#define CNT_OFF  0                         // [0..7] per-XCD ticket counters
#define CHO_OFF  8                         // elected xcd+1 (0 = unset)
#define ABT_OFF  9                         // abort flag
#define TAG_OFF  32                        // tags[24]
#define H1F_OFF  1024                      // u64[RD][512] fast  (8192 u32)
#define H1S_OFF  (H1F_OFF + RD * 512 * 2)  // u64[RD][512] slow
#define H2F_OFF  (H1S_OFF + RD * 512 * 2)  // u64[RD][128] fast  (2048 u32)
#define H2S_OFF  (H2F_OFF + RD * 128 * 2)  // u64[RD][128] slow
#define WS_WORDS (H2S_OFF + RD * 128 * 2)  // 21504 u32 = 86 KB

typedef unsigned int uint4v __attribute__((ext_vector_type(4)));

__device__ __forceinline__ float sigm(float x) { return 1.0f / (1.0f + __expf(-x)); }
__device__ __forceinline__ float tanh_fast(float x) { return 1.0f - 2.0f / (__expf(2.0f * x) + 1.0f); }

// ---- scoped access helpers ------------------------------------------------
__device__ __forceinline__ unsigned ld_u32_sc1(const unsigned* p) {
    unsigned r;
    asm volatile("global_load_dword %0, %1, off sc1\n\ts_waitcnt vmcnt(0)"
                 : "=v"(r) : "v"(p) : "memory");
    return r;
}
__device__ __forceinline__ void st_u32_sc1(unsigned* p, unsigned v) {
    asm volatile("global_store_dword %0, %1, off sc1" :: "v"(p), "v"(v) : "memory");
}
__device__ __forceinline__ void st_u64_sc0(unsigned long long* p, unsigned long long v) {
    asm volatile("global_store_dwordx2 %0, %1, off sc0" :: "v"(p), "v"(v) : "memory");
}
__device__ __forceinline__ void st_u64_sc1(unsigned long long* p, unsigned long long v) {
    asm volatile("global_store_dwordx2 %0, %1, off sc1" :: "v"(p), "v"(v) : "memory");
}
__device__ __forceinline__ void ld2x16_sc0(const unsigned long long* p, uint4v& A, uint4v& B) {
    asm volatile("global_load_dwordx4 %0, %2, off sc0\n\t"
                 "global_load_dwordx4 %1, %3, off sc0\n\t"
                 "s_waitcnt vmcnt(0)"
                 : "=&v"(A), "=&v"(B) : "v"(p), "v"(p + 2) : "memory");
}
__device__ __forceinline__ void ld2x16_sc1(const unsigned long long* p, uint4v& A, uint4v& B) {
    asm volatile("global_load_dwordx4 %0, %2, off sc1\n\t"
                 "global_load_dwordx4 %1, %3, off sc1\n\t"
                 "s_waitcnt vmcnt(0)"
                 : "=&v"(A), "=&v"(B) : "v"(p), "v"(p + 2) : "memory");
}
__device__ __forceinline__ void ld1x16_sc0(const unsigned long long* p, uint4v& A) {
    asm volatile("global_load_dwordx4 %0, %1, off sc0\n\ts_waitcnt vmcnt(0)"
                 : "=&v"(A) : "v"(p) : "memory");
}
__device__ __forceinline__ void ld1x16_sc1(const unsigned long long* p, uint4v& A) {
    asm volatile("global_load_dwordx4 %0, %1, off sc1\n\ts_waitcnt vmcnt(0)"
                 : "=&v"(A) : "v"(p) : "memory");
}

__global__ void lstm_init(unsigned int* ws)
{
    int i = blockIdx.x * blockDim.x + threadIdx.x;
    if (i < WS_WORDS) ws[i] = 0u;
}

__global__ __launch_bounds__(BLK) void lstm_persist(
    const float* __restrict__ x,      // [32768][128]
    const float* __restrict__ Wih1,   // [2048][128]
    const float* __restrict__ Whh1,   // [2048][512]
    const float* __restrict__ bih1,
    const float* __restrict__ bhh1,
    const float* __restrict__ Wih2,   // [512][512]
    const float* __restrict__ Whh2,   // [512][128]
    const float* __restrict__ bih2,
    const float* __restrict__ bhh2,
    float* __restrict__ out,          // [32768][128]
    unsigned int* ws)
{
    const int tid  = threadIdx.x;
    const int wave = tid >> 6;
    const int lane = tid & 63;

    __shared__ __align__(16) float h1buf[2][16 * 36];   // chunked, stride 36
    __shared__ __align__(16) float h2buf[2][8 * 20];    // entry stride 20
    __shared__ unsigned s_role[1];
    __shared__ unsigned s_ab[1];

    unsigned* cnt  = ws + CNT_OFF;
    unsigned* cho  = ws + CHO_OFF;
    unsigned* abf  = ws + ABT_OFF;
    unsigned* tags = ws + TAG_OFF;
    unsigned long long* h1f = (unsigned long long*)(ws + H1F_OFF);
    unsigned long long* h1s = (unsigned long long*)(ws + H1S_OFF);
    unsigned long long* h2f = (unsigned long long*)(ws + H2F_OFF);
    unsigned long long* h2s = (unsigned long long*)(ws + H2S_OFF);

    // ---- election: first XCD to accumulate NWG tickets wins --------------
    if (tid == 0) {
        s_ab[0] = 0u;
        unsigned xcc;
        asm volatile("s_getreg_b32 %0, hwreg(20, 0, 32)" : "=s"(xcc));  // XCC_ID
        xcc &= 7u;
        unsigned role = 0xFFFFu;
        unsigned tkt = __hip_atomic_fetch_add(&cnt[xcc], 1u,
                           __ATOMIC_RELAXED, __HIP_MEMORY_SCOPE_AGENT);
        if (tkt < NWG) {
            if (tkt == NWG - 1) {
                unsigned exp = 0u;
                __hip_atomic_compare_exchange_strong(cho, &exp, xcc + 1u,
                    __ATOMIC_RELAXED, __ATOMIC_RELAXED, __HIP_MEMORY_SCOPE_AGENT);
            }
            unsigned c, sp = 0;
            for (;;) {
                c = __hip_atomic_load(cho, __ATOMIC_RELAXED, __HIP_MEMORY_SCOPE_AGENT);
                if (c != 0u) break;
                __builtin_amdgcn_s_sleep(2);
                if (++sp > (1u << 22)) { c = 0xFFu; break; }
            }
            if (c == xcc + 1u) role = tkt;
        }
        s_role[0] = role;
    }
    __syncthreads();
    const int role = (int)s_role[0];
    if (role >= NWG) return;

    const bool isL1 = role < L1WG;

    if (isL1) {
        // ================= LAYER 1: 32 h-indices per WG ====================
        const int rt = tid >> 4;          // 0..31 h-index
        const int ct = tid & 15;          // 0..15 col-tile (32 prim + 8 sec)
        const int hb = role * 32;

        float wA[4][32], wB[4][8], bia[4];
#pragma unroll
        for (int q = 0; q < 4; ++q) {
            const int grow = q * 512 + hb + rt;
            const float4* pa = (const float4*)(Whh1 + (size_t)grow * 512 + ct * 32);
#pragma unroll
            for (int c = 0; c < 8; ++c) {
                float4 f = pa[c];
                wA[q][c * 4 + 0] = f.x; wA[q][c * 4 + 1] = f.y;
                wA[q][c * 4 + 2] = f.z; wA[q][c * 4 + 3] = f.w;
            }
            const float4* pb = (const float4*)(Wih1 + (size_t)grow * 128 + ct * 8);
            float4 b0 = pb[0], b1 = pb[1];
            wB[q][0] = b0.x; wB[q][1] = b0.y; wB[q][2] = b0.z; wB[q][3] = b0.w;
            wB[q][4] = b1.x; wB[q][5] = b1.y; wB[q][6] = b1.z; wB[q][7] = b1.w;
            bia[q] = bih1[grow] + bhh1[grow];
        }

        float cst = 0.0f;
        float4 vx0 = *(const float4*)(x + ct * 8);
        float4 vx1 = *(const float4*)(x + ct * 8 + 4);
        __syncthreads();   // s_ab visible

        for (int n = 0; n < T_STEPS; ++n) {
            // ---- wave 3: overwrite guard, every 4th step, off crit path --
            if (wave == 3 && n >= 8 && (n & 3) == 0 && lane < NWG) {
                const int thr = n - 3;
                unsigned sp = 0;
                for (;;) {
                    int ok = ((int)ld_u32_sc1(&tags[lane]) >= thr);
                    if (__all(ok)) break;
                    if ((++sp & 255u) == 0u) {
                        if (ld_u32_sc1(abf) != 0u) { s_ab[0] = 1u; break; }
                        if (sp >= (1u << 21)) { st_u32_sc1(abf, 1u); s_ab[0] = 1u; break; }
                    }
                }
            }
            // ---- waves 0/1: poll+merge+stage h1[n-1] (tag == n) ----------
            if (wave < 2) {
                const size_t off = (size_t)((n - 1) & (RD - 1)) * 512 + wave * 256 + lane * 4;
                const unsigned long long* pf = h1f + off;
                const unsigned long long* ps = h1s + off;
                const unsigned e = (unsigned)n;
                uint4v A, B;
                unsigned sp = 0;
                for (;;) {
                    ld2x16_sc0(pf, A, B);
                    int ok = (A.y == e) & (A.w == e) & (B.y == e) & (B.w == e);
                    if (__all(ok)) break;
                    if ((++sp & 7u) == 0u) {
                        uint4v C, D;
                        ld2x16_sc1(ps, C, D);
                        if (A.y != e) { A.x = C.x; A.y = C.y; }
                        if (A.w != e) { A.z = C.z; A.w = C.w; }
                        if (B.y != e) { B.x = D.x; B.y = D.y; }
                        if (B.w != e) { B.z = D.z; B.w = D.w; }
                        ok = (A.y == e) & (A.w == e) & (B.y == e) & (B.w == e);
                        if (__all(ok)) break;
                        if ((sp & 2047u) == 0u) {
                            if (ld_u32_sc1(abf) != 0u) { s_ab[0] = 1u; break; }
                            if (sp >= (1u << 22)) { st_u32_sc1(abf, 1u); s_ab[0] = 1u; break; }
                        }
                    }
                }
                const int g = wave * 256 + lane * 4;
                float4 vals = make_float4(__uint_as_float(A.x), __uint_as_float(A.z),
                                          __uint_as_float(B.x), __uint_as_float(B.z));
                *(float4*)&h1buf[n & 1][(g >> 5) * 36 + (g & 31)] = vals;
            }

            __syncthreads();
            if (s_ab[0]) break;
            if (tid == 0) st_u32_sc1(&tags[role], (unsigned)(n + 1));

            // ---- compute: 4 gates x (32 prim + 8 sec) cols ---------------
            float acc0 = 0.f, acc1 = 0.f, acc2 = 0.f, acc3 = 0.f;
            const float* hv = &h1buf[n & 1][ct * 36];
#pragma unroll
            for (int c = 0; c < 8; ++c) {
                float4 h4 = *(const float4*)(hv + c * 4);
                acc0 = fmaf(wA[0][c*4+0], h4.x, acc0); acc0 = fmaf(wA[0][c*4+1], h4.y, acc0);
                acc0 = fmaf(wA[0][c*4+2], h4.z, acc0); acc0 = fmaf(wA[0][c*4+3], h4.w, acc0);
                acc1 = fmaf(wA[1][c*4+0], h4.x, acc1); acc1 = fmaf(wA[1][c*4+1], h4.y, acc1);
                acc1 = fmaf(wA[1][c*4+2], h4.z, acc1); acc1 = fmaf(wA[1][c*4+3], h4.w, acc1);
                acc2 = fmaf(wA[2][c*4+0], h4.x, acc2); acc2 = fmaf(wA[2][c*4+1], h4.y, acc2);
                acc2 = fmaf(wA[2][c*4+2], h4.z, acc2); acc2 = fmaf(wA[2][c*4+3], h4.w, acc2);
                acc3 = fmaf(wA[3][c*4+0], h4.x, acc3); acc3 = fmaf(wA[3][c*4+1], h4.y, acc3);
                acc3 = fmaf(wA[3][c*4+2], h4.z, acc3); acc3 = fmaf(wA[3][c*4+3], h4.w, acc3);
            }
            {
                float sx[8] = { vx0.x, vx0.y, vx0.z, vx0.w, vx1.x, vx1.y, vx1.z, vx1.w };
#pragma unroll
                for (int j = 0; j < 8; ++j) {
                    acc0 = fmaf(wB[0][j], sx[j], acc0);
                    acc1 = fmaf(wB[1][j], sx[j], acc1);
                    acc2 = fmaf(wB[2][j], sx[j], acc2);
                    acc3 = fmaf(wB[3][j], sx[j], acc3);
                }
            }
            {   // prefetch next x row
                const int tn = (n + 1 < T_STEPS) ? (n + 1) : (T_STEPS - 1);
                vx0 = *(const float4*)(x + (size_t)tn * 128 + ct * 8);
                vx1 = *(const float4*)(x + (size_t)tn * 128 + ct * 8 + 4);
            }
#pragma unroll
            for (int m = 8; m >= 1; m >>= 1) {
                acc0 += __shfl_xor(acc0, m, 64);
                acc1 += __shfl_xor(acc1, m, 64);
                acc2 += __shfl_xor(acc2, m, 64);
                acc3 += __shfl_xor(acc3, m, 64);
            }
            const float ii = sigm(acc0 + bia[0]);
            const float ff = sigm(acc1 + bia[1]);
            const float g2 = tanh_fast(acc2 + bia[2]);
            const float oo = sigm(acc3 + bia[3]);
            cst = ff * cst + ii * g2;
            const float h = oo * tanh_fast(cst);

            if (ct == 0) {
                const unsigned long long pair =
                    ((unsigned long long)(unsigned)(n + 1) << 32) |
                    (unsigned long long)__float_as_uint(h);
                const size_t off = (size_t)(n & (RD - 1)) * 512 + hb + rt;
                st_u64_sc0(&h1f[off], pair);
                st_u64_sc1(&h1s[off], pair);
            }
        }
    } else {
        // ================= LAYER 2: 16 h-indices per WG ====================
        const int rt  = tid >> 5;         // 0..15
        const int ct  = tid & 31;         // 0..31 (16 prim + 4 sec cols)
        const int hb2 = (role - L1WG) * 16;

        float wA[4][16], wB[4][4], bia[4];
#pragma unroll
        for (int q = 0; q < 4; ++q) {
            const int grow = q * 128 + hb2 + rt;
            const float4* pa = (const float4*)(Wih2 + (size_t)grow * 512 + ct * 16);
#pragma unroll
            for (int c = 0; c < 4; ++c) {
                float4 f = pa[c];
                wA[q][c * 4 + 0] = f.x; wA[q][c * 4 + 1] = f.y;
                wA[q][c * 4 + 2] = f.z; wA[q][c * 4 + 3] = f.w;
            }
            float4 b0 = *(const float4*)(Whh2 + (size_t)grow * 128 + ct * 4);
            wB[q][0] = b0.x; wB[q][1] = b0.y; wB[q][2] = b0.z; wB[q][3] = b0.w;
            bia[q] = bih2[grow] + bhh2[grow];
        }

        float cst = 0.0f;
        __syncthreads();   // s_ab visible

        for (int n = 1; n <= T_STEPS; ++n) {
            const int tau = n - 1;
            if (wave == 3 && n >= 8 && (n & 3) == 0 && lane < NWG) {
                const int thr = n - 3;
                unsigned sp = 0;
                for (;;) {
                    int ok = ((int)ld_u32_sc1(&tags[lane]) >= thr);
                    if (__all(ok)) break;
                    if ((++sp & 255u) == 0u) {
                        if (ld_u32_sc1(abf) != 0u) { s_ab[0] = 1u; break; }
                        if (sp >= (1u << 21)) { st_u32_sc1(abf, 1u); s_ab[0] = 1u; break; }
                    }
                }
            }
            // ---- waves 0/1: poll+merge+stage h1[tau] (tag == n) ----------
            if (wave < 2) {
                const size_t off = (size_t)(tau & (RD - 1)) * 512 + wave * 256 + lane * 4;
                const unsigned long long* pf = h1f + off;
                const unsigned long long* ps = h1s + off;
                const unsigned e = (unsigned)n;
                uint4v A, B;
                unsigned sp = 0;
                for (;;) {
                    ld2x16_sc0(pf, A, B);
                    int ok = (A.y == e) & (A.w == e) & (B.y == e) & (B.w == e);
                    if (__all(ok)) break;
                    if ((++sp & 7u) == 0u) {
                        uint4v C, D;
                        ld2x16_sc1(ps, C, D);
                        if (A.y != e) { A.x = C.x; A.y = C.y; }
                        if (A.w != e) { A.z = C.z; A.w = C.w; }
                        if (B.y != e) { B.x = D.x; B.y = D.y; }
                        if (B.w != e) { B.z = D.z; B.w = D.w; }
                        ok = (A.y == e) & (A.w == e) & (B.y == e) & (B.w == e);
                        if (__all(ok)) break;
                        if ((sp & 2047u) == 0u) {
                            if (ld_u32_sc1(abf) != 0u) { s_ab[0] = 1u; break; }
                            if (sp >= (1u << 22)) { st_u32_sc1(abf, 1u); s_ab[0] = 1u; break; }
                        }
                    }
                }
                const int g = wave * 256 + lane * 4;
                float4 vals = make_float4(__uint_as_float(A.x), __uint_as_float(A.z),
                                          __uint_as_float(B.x), __uint_as_float(B.z));
                *(float4*)&h1buf[n & 1][(g >> 5) * 36 + (g & 31)] = vals;
            }
            // ---- wave 2: poll+merge+stage h2[tau-1] (tag == tau) ---------
            if (wave == 2) {
                const size_t off = (size_t)((tau - 1) & (RD - 1)) * 128 + lane * 2;
                const unsigned long long* pf = h2f + off;
                const unsigned long long* ps = h2s + off;
                const unsigned e = (unsigned)tau;
                uint4v A;
                unsigned sp = 0;
                for (;;) {
                    ld1x16_sc0(pf, A);
                    int ok = (A.y == e) & (A.w == e);
                    if (__all(ok)) break;
                    if ((++sp & 7u) == 0u) {
                        uint4v C;
                        ld1x16_sc1(ps, C);
                        if (A.y != e) { A.x = C.x; A.y = C.y; }
                        if (A.w != e) { A.z = C.z; A.w = C.w; }
                        ok = (A.y == e) & (A.w == e);
                        if (__all(ok)) break;
                        if ((sp & 2047u) == 0u) {
                            if (ld_u32_sc1(abf) != 0u) { s_ab[0] = 1u; break; }
                            if (sp >= (1u << 22)) { st_u32_sc1(abf, 1u); s_ab[0] = 1u; break; }
                        }
                    }
                }
                const int pi = lane * 2;
                float2 v2 = make_float2(__uint_as_float(A.x), __uint_as_float(A.z));
                *(float2*)&h2buf[n & 1][(pi >> 4) * 20 + (pi & 15)] = v2;
            }

            __syncthreads();
            if (s_ab[0]) break;
            if (tid == 0) st_u32_sc1(&tags[role], (unsigned)(n + 1));

            // ---- compute: 4 gates x (16 prim + 4 sec) --------------------
            float acc0 = 0.f, acc1 = 0.f, acc2 = 0.f, acc3 = 0.f;
            const float* hv = &h1buf[n & 1][(ct >> 1) * 36 + (ct & 1) * 16];
#pragma unroll
            for (int c = 0; c < 4; ++c) {
                float4 h4 = *(const float4*)(hv + c * 4);
                acc0 = fmaf(wA[0][c*4+0], h4.x, acc0); acc0 = fmaf(wA[0][c*4+1], h4.y, acc0);
                acc0 = fmaf(wA[0][c*4+2], h4.z, acc0); acc0 = fmaf(wA[0][c*4+3], h4.w, acc0);
                acc1 = fmaf(wA[1][c*4+0], h4.x, acc1); acc1 = fmaf(wA[1][c*4+1], h4.y, acc1);
                acc1 = fmaf(wA[1][c*4+2], h4.z, acc1); acc1 = fmaf(wA[1][c*4+3], h4.w, acc1);
                acc2 = fmaf(wA[2][c*4+0], h4.x, acc2); acc2 = fmaf(wA[2][c*4+1], h4.y, acc2);
                acc2 = fmaf(wA[2][c*4+2], h4.z, acc2); acc2 = fmaf(wA[2][c*4+3], h4.w, acc2);
                acc3 = fmaf(wA[3][c*4+0], h4.x, acc3); acc3 = fmaf(wA[3][c*4+1], h4.y, acc3);
                acc3 = fmaf(wA[3][c*4+2], h4.z, acc3); acc3 = fmaf(wA[3][c*4+3], h4.w, acc3);
            }
            {
                float4 s4 = *(const float4*)&h2buf[n & 1][(ct >> 2) * 20 + (ct & 3) * 4];
                float sv[4] = { s4.x, s4.y, s4.z, s4.w };
#pragma unroll
                for (int j = 0; j < 4; ++j) {
                    acc0 = fmaf(wB[0][j], sv[j], acc0);
                    acc1 = fmaf(wB[1][j], sv[j], acc1);
                    acc2 = fmaf(wB[2][j], sv[j], acc2);
                    acc3 = fmaf(wB[3][j], sv[j], acc3);
                }
            }
#pragma unroll
            for (int m = 16; m >= 1; m >>= 1) {
                acc0 += __shfl_xor(acc0, m, 64);
                acc1 += __shfl_xor(acc1, m, 64);
                acc2 += __shfl_xor(acc2, m, 64);
                acc3 += __shfl_xor(acc3, m, 64);
            }
            const float ii = sigm(acc0 + bia[0]);
            const float ff = sigm(acc1 + bia[1]);
            const float g2 = tanh_fast(acc2 + bia[2]);
            const float oo = sigm(acc3 + bia[3]);
            cst = ff * cst + ii * g2;
            const float h = oo * tanh_fast(cst);

            if (ct == 0) {
                const unsigned long long pair =
                    ((unsigned long long)(unsigned)n << 32) |
                    (unsigned long long)__float_as_uint(h);
                const size_t off = (size_t)(tau & (RD - 1)) * 128 + hb2 + rt;
                st_u64_sc0(&h2f[off], pair);
                st_u64_sc1(&h2s[off], pair);
                out[(size_t)tau * 128 + hb2 + rt] = h;
            }
        }
    }
}

extern "C" void kernel_launch(void* const* d_in, const int* in_sizes, int n_in,
                              void* d_out, int out_size, void* d_ws, size_t ws_size,
                              hipStream_t stream)
{
    const float* x    = (const float*)d_in[0];
    const float* Wih1 = (const float*)d_in[1];
    const float* Whh1 = (const float*)d_in[2];
    const float* bih1 = (const float*)d_in[3];
    const float* bhh1 = (const float*)d_in[4];
    const float* Wih2 = (const float*)d_in[5];
    const float* Whh2 = (const float*)d_in[6];
    const float* bih2 = (const float*)d_in[7];
    const float* bhh2 = (const float*)d_in[8];
    unsigned int* ws  = (unsigned int*)d_ws;

    hipLaunchKernelGGL(lstm_init, dim3(96), dim3(256), 0, stream, ws);
    hipLaunchKernelGGL(lstm_persist, dim3(GRID), dim3(BLK), 0, stream,
                       x, Wih1, Whh1, bih1, bhh1, Wih2, Whh2, bih2, bhh2,
                       (float*)d_out, ws);
}